// Round 1
// baseline (1666.396 us; speedup 1.0000x reference)
//
#include <hip/hip_runtime.h>
#include <hip/hip_bf16.h>
#include <math.h>

#define N_NODESC 100000
#define N_EDGESC 1600000
#define N_GRAPHSC 128
#define IN_DIMC 64
#define HIDC 128
#define OUT_DIMC 16
#define NUM_ITERSC 4
#define GAMMAC 0.1f
#define EPSC 0.1f

// Build combined transposed weight MT[k][c], k in [0,256): k<128 -> aW[c][k] = W[c][k]-W[k][c]-gamma*I; k>=128 -> lin_w[c][k-128]
__global__ __launch_bounds__(256) void k_weights(const float* __restrict__ W,
                                                 const float* __restrict__ lin_w,
                                                 float* __restrict__ MT) {
  int idx = blockIdx.x * 256 + threadIdx.x;
  if (idx >= 2 * HIDC * HIDC) return;
  int k = idx >> 7;
  int c = idx & (HIDC - 1);
  float v;
  if (k < HIDC) {
    v = W[c * HIDC + k] - W[k * HIDC + c] - ((k == c) ? GAMMAC : 0.0f);
  } else {
    v = lin_w[c * HIDC + (k - HIDC)];
  }
  MT[idx] = v;
}

// h = x @ emb_w.T + emb_b   [N,64]@[64,128]
__global__ __launch_bounds__(256) void k_embed(const float* __restrict__ x,
                                               const float* __restrict__ emb_w,
                                               const float* __restrict__ emb_b,
                                               float* __restrict__ h) {
  __shared__ float wl[HIDC][IN_DIMC + 1];
  __shared__ float xl[8][IN_DIMC];
  int tid = threadIdx.x;
  for (int i = tid; i < HIDC * IN_DIMC; i += 256) {
    wl[i >> 6][i & 63] = emb_w[i];
  }
  int c = tid & (HIDC - 1);
  int half = tid >> 7;
  float bias = emb_b[c];
  int row0 = blockIdx.x * 64;
  __syncthreads();
  for (int rb = 0; rb < 64; rb += 8) {
    __syncthreads();
    for (int i = tid; i < 8 * IN_DIMC; i += 256) {
      int r = i >> 6;
      int gr = row0 + rb + r;
      xl[r][i & 63] = (gr < N_NODESC) ? x[(size_t)gr * IN_DIMC + (i & 63)] : 0.0f;
    }
    __syncthreads();
#pragma unroll
    for (int rr = 0; rr < 4; ++rr) {
      int r = half * 4 + rr;
      int gr = row0 + rb + r;
      if (gr < N_NODESC) {
        float acc = bias;
#pragma unroll
        for (int k = 0; k < IN_DIMC; ++k) acc = fmaf(xl[r][k], wl[c][k], acc);
        h[(size_t)gr * HIDC + c] = acc;
      }
    }
  }
}

__global__ __launch_bounds__(256) void k_count(const int* __restrict__ dst, int* __restrict__ cnt) {
  int e = blockIdx.x * 256 + threadIdx.x;
  if (e < N_EDGESC) atomicAdd(&cnt[dst[e]], 1);
}

// single-block exclusive scan; in: cnt (in cnt_cursor), out: rowptr and cursor(=rowptr copy, in-place over cnt)
__global__ __launch_bounds__(1024) void k_scan(int* __restrict__ cnt_cursor, int* __restrict__ rowptr) {
  __shared__ int buf[1024];
  __shared__ int carry;
  int tid = threadIdx.x;
  if (tid == 0) carry = 0;
  __syncthreads();
  for (int base = 0; base < N_NODESC; base += 1024) {
    int i = base + tid;
    int v = (i < N_NODESC) ? cnt_cursor[i] : 0;
    buf[tid] = v;
    __syncthreads();
    for (int off = 1; off < 1024; off <<= 1) {
      int t = (tid >= off) ? buf[tid - off] : 0;
      __syncthreads();
      buf[tid] += t;
      __syncthreads();
    }
    int excl = carry + buf[tid] - v;
    if (i < N_NODESC) {
      rowptr[i] = excl;
      cnt_cursor[i] = excl;
    }
    __syncthreads();
    if (tid == 0) carry += buf[1023];
    __syncthreads();
  }
  if (threadIdx.x == 0) rowptr[N_NODESC] = carry;
}

__global__ __launch_bounds__(256) void k_fill(const int* __restrict__ src, const int* __restrict__ dst,
                                              int* __restrict__ cursor, int* __restrict__ colidx) {
  int e = blockIdx.x * 256 + threadIdx.x;
  if (e < N_EDGESC) {
    int p = atomicAdd(&cursor[dst[e]], 1);
    colidx[p] = src[e];
  }
}

// agg[d] = sum over in-edges of h[src]; one wave per node, 2 cols per lane
__global__ __launch_bounds__(256) void k_gather(const float* __restrict__ h,
                                                const int* __restrict__ rowptr,
                                                const int* __restrict__ colidx,
                                                float* __restrict__ agg) {
  int node = blockIdx.x * 4 + (threadIdx.x >> 6);
  int lane = threadIdx.x & 63;
  if (node >= N_NODESC) return;
  int beg = rowptr[node];
  int end = rowptr[node + 1];
  float2 acc = make_float2(0.f, 0.f);
  int e = beg;
  for (; e + 2 <= end; e += 2) {
    int s0 = colidx[e], s1 = colidx[e + 1];
    float2 v0 = *(const float2*)(h + (size_t)s0 * HIDC + 2 * lane);
    float2 v1 = *(const float2*)(h + (size_t)s1 * HIDC + 2 * lane);
    acc.x += v0.x + v1.x;
    acc.y += v0.y + v1.y;
  }
  if (e < end) {
    int s0 = colidx[e];
    float2 v0 = *(const float2*)(h + (size_t)s0 * HIDC + 2 * lane);
    acc.x += v0.x;
    acc.y += v0.y;
  }
  *(float2*)(agg + (size_t)node * HIDC + 2 * lane) = acc;
}

// conv = [h|agg] @ MT (K=256), h += eps*tanh(conv + b). 32 rows/block, thread tile 4r x 4c.
__global__ __launch_bounds__(256) void k_update(float* __restrict__ h,
                                                const float* __restrict__ agg,
                                                const float* __restrict__ MT,
                                                const float* __restrict__ asym_b) {
  __shared__ __align__(16) float wl[64][HIDC + 4];  // [k][c] chunk, stride 132
  __shared__ __align__(16) float rl[32][64 + 4];    // [r][k] chunk, stride 68
  int tid = threadIdx.x;
  int tc = tid & 31;
  int tr = tid >> 5;
  int row0 = blockIdx.x * 32;
  float acc[4][4];
#pragma unroll
  for (int j = 0; j < 4; ++j) {
    acc[j][0] = acc[j][1] = acc[j][2] = acc[j][3] = 0.f;
  }
  for (int kc = 0; kc < 4; ++kc) {
    __syncthreads();
    for (int i = tid; i < 64 * HIDC; i += 256) {
      int k = i >> 7, c = i & (HIDC - 1);
      wl[k][c] = MT[(size_t)(kc * 64 + k) * HIDC + c];
    }
    const float* srcp = (kc < 2) ? h : agg;
    int coff = (kc & 1) * 64;
    for (int i = tid; i < 32 * 64; i += 256) {
      int r = i >> 6, kk = i & 63;
      rl[r][kk] = srcp[(size_t)(row0 + r) * HIDC + coff + kk];
    }
    __syncthreads();
#pragma unroll
    for (int k4 = 0; k4 < 64; k4 += 4) {
      float4 w0 = *(const float4*)&wl[k4 + 0][tc * 4];
      float4 w1 = *(const float4*)&wl[k4 + 1][tc * 4];
      float4 w2 = *(const float4*)&wl[k4 + 2][tc * 4];
      float4 w3 = *(const float4*)&wl[k4 + 3][tc * 4];
#pragma unroll
      for (int j = 0; j < 4; ++j) {
        float4 rv = *(const float4*)&rl[tr * 4 + j][k4];
        acc[j][0] = fmaf(rv.x, w0.x, fmaf(rv.y, w1.x, fmaf(rv.z, w2.x, fmaf(rv.w, w3.x, acc[j][0]))));
        acc[j][1] = fmaf(rv.x, w0.y, fmaf(rv.y, w1.y, fmaf(rv.z, w2.y, fmaf(rv.w, w3.y, acc[j][1]))));
        acc[j][2] = fmaf(rv.x, w0.z, fmaf(rv.y, w1.z, fmaf(rv.z, w2.z, fmaf(rv.w, w3.z, acc[j][2]))));
        acc[j][3] = fmaf(rv.x, w0.w, fmaf(rv.y, w1.w, fmaf(rv.z, w2.w, fmaf(rv.w, w3.w, acc[j][3]))));
      }
    }
  }
  float4 bias = *(const float4*)&asym_b[tc * 4];
#pragma unroll
  for (int j = 0; j < 4; ++j) {
    size_t r = (size_t)(row0 + tr * 4 + j);
    float4 hv = *(const float4*)&h[r * HIDC + tc * 4];
    float4 o;
    o.x = hv.x + EPSC * tanhf(acc[j][0] + bias.x);
    o.y = hv.y + EPSC * tanhf(acc[j][1] + bias.y);
    o.z = hv.z + EPSC * tanhf(acc[j][2] + bias.z);
    o.w = hv.w + EPSC * tanhf(acc[j][3] + bias.w);
    *(float4*)&h[r * HIDC + tc * 4] = o;
  }
}

__device__ __forceinline__ int lbound_batch(const int* __restrict__ a, int key) {
  int lo = 0, hi = N_NODESC;
  while (lo < hi) {
    int mid = (lo + hi) >> 1;
    if (a[mid] < key) lo = mid + 1;
    else hi = mid;
  }
  return lo;
}

// pool[g] = [add(128) | max(128) | mean(128)]
__global__ __launch_bounds__(128) void k_pool(const float* __restrict__ h,
                                              const int* __restrict__ batch,
                                              float* __restrict__ pool) {
  int g = blockIdx.x;
  int c = threadIdx.x;
  int lo = lbound_batch(batch, g);
  int hi = lbound_batch(batch, g + 1);
  float s = 0.f, m = -INFINITY;
  for (int i = lo; i < hi; ++i) {
    float v = h[(size_t)i * HIDC + c];
    s += v;
    m = fmaxf(m, v);
  }
  float cntf = (float)(hi - lo);
  float mean = s / fmaxf(cntf, 1.f);
  pool[g * 384 + c] = s;
  pool[g * 384 + 128 + c] = m;
  pool[g * 384 + 256 + c] = mean;
}

__global__ __launch_bounds__(192) void k_mlp1(const float* __restrict__ pool,
                                              const float* __restrict__ r1_w,
                                              const float* __restrict__ r1_b,
                                              float* __restrict__ g1) {
  __shared__ float gv[384];
  int g = blockIdx.x;
  for (int i = threadIdx.x; i < 384; i += 192) gv[i] = pool[g * 384 + i];
  __syncthreads();
  int j = threadIdx.x;
  float acc = r1_b[j];
  const float* wr = r1_w + (size_t)j * 384;
#pragma unroll 4
  for (int k = 0; k < 384; ++k) acc = fmaf(gv[k], wr[k], acc);
  g1[g * 192 + j] = (acc > 0.f) ? acc : 0.01f * acc;
}

__global__ __launch_bounds__(256) void k_mlp2(const float* __restrict__ g1,
                                              const float* __restrict__ r2_w,
                                              const float* __restrict__ r2_b,
                                              float* __restrict__ out) {
  int idx = blockIdx.x * 256 + threadIdx.x;
  if (idx >= N_GRAPHSC * OUT_DIMC) return;
  int g = idx >> 4;
  int o = idx & 15;
  float acc = r2_b[o];
  const float* wr = r2_w + o * 192;
  const float* gr = g1 + g * 192;
  for (int k = 0; k < 192; ++k) acc = fmaf(gr[k], wr[k], acc);
  out[idx] = (acc > 0.f) ? acc : 0.01f * acc;
}

extern "C" void kernel_launch(void* const* d_in, const int* in_sizes, int n_in,
                              void* d_out, int out_size, void* d_ws, size_t ws_size,
                              hipStream_t stream) {
  const float* x      = (const float*)d_in[0];
  const int*   ei     = (const int*)d_in[1];
  const int*   batch  = (const int*)d_in[2];
  const float* emb_w  = (const float*)d_in[3];
  const float* emb_b  = (const float*)d_in[4];
  const float* W      = (const float*)d_in[5];
  const float* asym_b = (const float*)d_in[6];
  const float* lin_w  = (const float*)d_in[7];
  const float* r1_w   = (const float*)d_in[8];
  const float* r1_b   = (const float*)d_in[9];
  const float* r2_w   = (const float*)d_in[10];
  const float* r2_b   = (const float*)d_in[11];
  float* out = (float*)d_out;

  char* ws = (char*)d_ws;
  size_t off = 0;
  auto alloc = [&](size_t bytes) -> char* {
    char* p = ws + off;
    off += (bytes + 255) & ~(size_t)255;
    return p;
  };
  float* h      = (float*)alloc((size_t)N_NODESC * HIDC * 4);   // 51.2 MB
  float* agg    = (float*)alloc((size_t)N_NODESC * HIDC * 4);   // 51.2 MB
  float* MT     = (float*)alloc((size_t)2 * HIDC * HIDC * 4);   // 128 KB
  int* rowptr   = (int*)alloc((size_t)(N_NODESC + 1) * 4);
  int* cursor   = (int*)alloc((size_t)N_NODESC * 4);
  int* colidx   = (int*)alloc((size_t)N_EDGESC * 4);            // 6.4 MB
  float* pool   = (float*)alloc((size_t)N_GRAPHSC * 3 * HIDC * 4);
  float* g1buf  = (float*)alloc((size_t)N_GRAPHSC * 192 * 4);
  (void)ws_size; (void)in_sizes; (void)n_in; (void)out_size;

  const int* srcv = ei;
  const int* dstv = ei + N_EDGESC;

  hipMemsetAsync(cursor, 0, (size_t)N_NODESC * 4, stream);
  k_weights<<<(2 * HIDC * HIDC + 255) / 256, 256, 0, stream>>>(W, lin_w, MT);
  k_embed<<<(N_NODESC + 63) / 64, 256, 0, stream>>>(x, emb_w, emb_b, h);
  k_count<<<(N_EDGESC + 255) / 256, 256, 0, stream>>>(dstv, cursor);
  k_scan<<<1, 1024, 0, stream>>>(cursor, rowptr);
  k_fill<<<(N_EDGESC + 255) / 256, 256, 0, stream>>>(srcv, dstv, cursor, colidx);
  for (int it = 0; it < NUM_ITERSC; ++it) {
    k_gather<<<N_NODESC / 4, 256, 0, stream>>>(h, rowptr, colidx, agg);
    k_update<<<N_NODESC / 32, 256, 0, stream>>>(h, agg, MT, asym_b);
  }
  k_pool<<<N_GRAPHSC, 128, 0, stream>>>(h, batch, pool);
  k_mlp1<<<N_GRAPHSC, 192, 0, stream>>>(pool, r1_w, r1_b, g1buf);
  k_mlp2<<<(N_GRAPHSC * OUT_DIMC + 255) / 256, 256, 0, stream>>>(g1buf, r2_w, r2_b, out);
}

// Round 2
// 1529.640 us; speedup vs baseline: 1.0894x; 1.0894x over previous
//
#include <hip/hip_runtime.h>
#include <hip/hip_bf16.h>
#include <math.h>

#define N_NODESC 100000
#define N_EDGESC 1600000
#define N_GRAPHSC 128
#define IN_DIMC 64
#define HIDC 128
#define OUT_DIMC 16
#define NUM_ITERSC 4
#define GAMMAC 0.1f
#define EPSC 0.1f
#define POOL_CHUNKS 8

// Build combined transposed weight MT[k][c], k in [0,256): k<128 -> aW[c][k] = W[c][k]-W[k][c]-gamma*I; k>=128 -> lin_w[c][k-128]
__global__ __launch_bounds__(256) void k_weights(const float* __restrict__ W,
                                                 const float* __restrict__ lin_w,
                                                 float* __restrict__ MT) {
  int idx = blockIdx.x * 256 + threadIdx.x;
  if (idx >= 2 * HIDC * HIDC) return;
  int k = idx >> 7;
  int c = idx & (HIDC - 1);
  float v;
  if (k < HIDC) {
    v = W[c * HIDC + k] - W[k * HIDC + c] - ((k == c) ? GAMMAC : 0.0f);
  } else {
    v = lin_w[c * HIDC + (k - HIDC)];
  }
  MT[idx] = v;
}

// h = x @ emb_w.T + emb_b   [N,64]@[64,128]
__global__ __launch_bounds__(256) void k_embed(const float* __restrict__ x,
                                               const float* __restrict__ emb_w,
                                               const float* __restrict__ emb_b,
                                               float* __restrict__ h) {
  __shared__ float wl[HIDC][IN_DIMC + 1];
  __shared__ float xl[8][IN_DIMC];
  int tid = threadIdx.x;
  for (int i = tid; i < HIDC * IN_DIMC; i += 256) {
    wl[i >> 6][i & 63] = emb_w[i];
  }
  int c = tid & (HIDC - 1);
  int half = tid >> 7;
  float bias = emb_b[c];
  int row0 = blockIdx.x * 64;
  __syncthreads();
  for (int rb = 0; rb < 64; rb += 8) {
    __syncthreads();
    for (int i = tid; i < 8 * IN_DIMC; i += 256) {
      int r = i >> 6;
      int gr = row0 + rb + r;
      xl[r][i & 63] = (gr < N_NODESC) ? x[(size_t)gr * IN_DIMC + (i & 63)] : 0.0f;
    }
    __syncthreads();
#pragma unroll
    for (int rr = 0; rr < 4; ++rr) {
      int r = half * 4 + rr;
      int gr = row0 + rb + r;
      if (gr < N_NODESC) {
        float acc = bias;
#pragma unroll
        for (int k = 0; k < IN_DIMC; ++k) acc = fmaf(xl[r][k], wl[c][k], acc);
        h[(size_t)gr * HIDC + c] = acc;
      }
    }
  }
}

__global__ __launch_bounds__(256) void k_count(const int* __restrict__ dst, int* __restrict__ cnt) {
  int e = blockIdx.x * 256 + threadIdx.x;
  if (e < N_EDGESC) atomicAdd(&cnt[dst[e]], 1);
}

// chunked exclusive scan: 1024 threads, ~98 elems each, one LDS scan of chunk totals
__global__ __launch_bounds__(1024) void k_scan(int* __restrict__ cnt_cursor, int* __restrict__ rowptr) {
  __shared__ int sums[1024];
  int tid = threadIdx.x;
  const int CH = (N_NODESC + 1023) / 1024;  // 98
  int beg = tid * CH;
  int end = beg + CH;
  if (end > N_NODESC) end = N_NODESC;
  int s = 0;
  for (int i = beg; i < end; ++i) s += cnt_cursor[i];
  sums[tid] = s;
  __syncthreads();
  for (int off = 1; off < 1024; off <<= 1) {
    int t = (tid >= off) ? sums[tid - off] : 0;
    __syncthreads();
    sums[tid] += t;
    __syncthreads();
  }
  int excl = sums[tid] - s;
  for (int i = beg; i < end; ++i) {
    int v = cnt_cursor[i];
    rowptr[i] = excl;
    cnt_cursor[i] = excl;
    excl += v;
  }
  if (tid == 1023) rowptr[N_NODESC] = excl;
}

__global__ __launch_bounds__(256) void k_fill(const int* __restrict__ src, const int* __restrict__ dst,
                                              int* __restrict__ cursor, int* __restrict__ colidx) {
  int e = blockIdx.x * 256 + threadIdx.x;
  if (e < N_EDGESC) {
    int p = atomicAdd(&cursor[dst[e]], 1);
    colidx[p] = src[e];
  }
}

// agg[d] = sum over in-edges of h[src]; one wave per node, 2 cols per lane
__global__ __launch_bounds__(256) void k_gather(const float* __restrict__ h,
                                                const int* __restrict__ rowptr,
                                                const int* __restrict__ colidx,
                                                float* __restrict__ agg) {
  int node = blockIdx.x * 4 + (threadIdx.x >> 6);
  int lane = threadIdx.x & 63;
  if (node >= N_NODESC) return;
  int beg = rowptr[node];
  int end = rowptr[node + 1];
  float2 acc = make_float2(0.f, 0.f);
  int e = beg;
  for (; e + 2 <= end; e += 2) {
    int s0 = colidx[e], s1 = colidx[e + 1];
    float2 v0 = *(const float2*)(h + (size_t)s0 * HIDC + 2 * lane);
    float2 v1 = *(const float2*)(h + (size_t)s1 * HIDC + 2 * lane);
    acc.x += v0.x + v1.x;
    acc.y += v0.y + v1.y;
  }
  if (e < end) {
    int s0 = colidx[e];
    float2 v0 = *(const float2*)(h + (size_t)s0 * HIDC + 2 * lane);
    acc.x += v0.x;
    acc.y += v0.y;
  }
  *(float2*)(agg + (size_t)node * HIDC + 2 * lane) = acc;
}

// conv = [h|agg] @ MT (K=256), h += eps*tanh(conv + b). 32 rows/block, thread tile 4r x 4c.
__global__ __launch_bounds__(256) void k_update(float* __restrict__ h,
                                                const float* __restrict__ agg,
                                                const float* __restrict__ MT,
                                                const float* __restrict__ asym_b) {
  __shared__ __align__(16) float wl[64][HIDC + 4];  // [k][c] chunk, stride 132
  __shared__ __align__(16) float rl[32][64 + 4];    // [r][k] chunk, stride 68
  int tid = threadIdx.x;
  int tc = tid & 31;
  int tr = tid >> 5;
  int row0 = blockIdx.x * 32;
  float acc[4][4];
#pragma unroll
  for (int j = 0; j < 4; ++j) {
    acc[j][0] = acc[j][1] = acc[j][2] = acc[j][3] = 0.f;
  }
  for (int kc = 0; kc < 4; ++kc) {
    __syncthreads();
    for (int i = tid; i < 64 * HIDC; i += 256) {
      int k = i >> 7, c = i & (HIDC - 1);
      wl[k][c] = MT[(size_t)(kc * 64 + k) * HIDC + c];
    }
    const float* srcp = (kc < 2) ? h : agg;
    int coff = (kc & 1) * 64;
    for (int i = tid; i < 32 * 64; i += 256) {
      int r = i >> 6, kk = i & 63;
      rl[r][kk] = srcp[(size_t)(row0 + r) * HIDC + coff + kk];
    }
    __syncthreads();
#pragma unroll
    for (int k4 = 0; k4 < 64; k4 += 4) {
      float4 w0 = *(const float4*)&wl[k4 + 0][tc * 4];
      float4 w1 = *(const float4*)&wl[k4 + 1][tc * 4];
      float4 w2 = *(const float4*)&wl[k4 + 2][tc * 4];
      float4 w3 = *(const float4*)&wl[k4 + 3][tc * 4];
#pragma unroll
      for (int j = 0; j < 4; ++j) {
        float4 rv = *(const float4*)&rl[tr * 4 + j][k4];
        acc[j][0] = fmaf(rv.x, w0.x, fmaf(rv.y, w1.x, fmaf(rv.z, w2.x, fmaf(rv.w, w3.x, acc[j][0]))));
        acc[j][1] = fmaf(rv.x, w0.y, fmaf(rv.y, w1.y, fmaf(rv.z, w2.y, fmaf(rv.w, w3.y, acc[j][1]))));
        acc[j][2] = fmaf(rv.x, w0.z, fmaf(rv.y, w1.z, fmaf(rv.z, w2.z, fmaf(rv.w, w3.z, acc[j][2]))));
        acc[j][3] = fmaf(rv.x, w0.w, fmaf(rv.y, w1.w, fmaf(rv.z, w2.w, fmaf(rv.w, w3.w, acc[j][3]))));
      }
    }
  }
  float4 bias = *(const float4*)&asym_b[tc * 4];
#pragma unroll
  for (int j = 0; j < 4; ++j) {
    size_t r = (size_t)(row0 + tr * 4 + j);
    float4 hv = *(const float4*)&h[r * HIDC + tc * 4];
    float4 o;
    o.x = hv.x + EPSC * tanhf(acc[j][0] + bias.x);
    o.y = hv.y + EPSC * tanhf(acc[j][1] + bias.y);
    o.z = hv.z + EPSC * tanhf(acc[j][2] + bias.z);
    o.w = hv.w + EPSC * tanhf(acc[j][3] + bias.w);
    *(float4*)&h[r * HIDC + tc * 4] = o;
  }
}

__device__ __forceinline__ int lbound_batch(const int* __restrict__ a, int key) {
  int lo = 0, hi = N_NODESC;
  while (lo < hi) {
    int mid = (lo + hi) >> 1;
    if (a[mid] < key) lo = mid + 1;
    else hi = mid;
  }
  return lo;
}

// stage 1: partial [sum|max] per (graph, chunk); grid = G*POOL_CHUNKS blocks of 128
__global__ __launch_bounds__(128) void k_pool1(const float* __restrict__ h,
                                               const int* __restrict__ batch,
                                               float* __restrict__ part) {
  int g = blockIdx.x / POOL_CHUNKS;
  int j = blockIdx.x % POOL_CHUNKS;
  int c = threadIdx.x;
  int lo = lbound_batch(batch, g);
  int hi = lbound_batch(batch, g + 1);
  int n = hi - lo;
  int ch = (n + POOL_CHUNKS - 1) / POOL_CHUNKS;
  int b = lo + j * ch;
  int e = b + ch;
  if (e > hi) e = hi;
  float s = 0.f, m = -INFINITY;
  for (int i = b; i < e; ++i) {
    float v = h[(size_t)i * HIDC + c];
    s += v;
    m = fmaxf(m, v);
  }
  size_t o = ((size_t)g * POOL_CHUNKS + j) * 256;
  part[o + c] = s;
  part[o + 128 + c] = m;
}

// stage 2: combine chunks -> pool[g] = [add | max | mean], plus count
__global__ __launch_bounds__(128) void k_pool2(const float* __restrict__ part,
                                               const int* __restrict__ batch,
                                               float* __restrict__ pool) {
  int g = blockIdx.x;
  int c = threadIdx.x;
  float s = 0.f, m = -INFINITY;
#pragma unroll
  for (int j = 0; j < POOL_CHUNKS; ++j) {
    size_t o = ((size_t)g * POOL_CHUNKS + j) * 256;
    s += part[o + c];
    m = fmaxf(m, part[o + 128 + c]);
  }
  int lo = lbound_batch(batch, g);
  int hi = lbound_batch(batch, g + 1);
  float cntf = (float)(hi - lo);
  pool[g * 384 + c] = s;
  pool[g * 384 + 128 + c] = m;
  pool[g * 384 + 256 + c] = s / fmaxf(cntf, 1.f);
}

__global__ __launch_bounds__(192) void k_mlp1(const float* __restrict__ pool,
                                              const float* __restrict__ r1_w,
                                              const float* __restrict__ r1_b,
                                              float* __restrict__ g1) {
  __shared__ float gv[384];
  int g = blockIdx.x;
  for (int i = threadIdx.x; i < 384; i += 192) gv[i] = pool[g * 384 + i];
  __syncthreads();
  int j = threadIdx.x;
  float acc = r1_b[j];
  const float* wr = r1_w + (size_t)j * 384;
#pragma unroll 4
  for (int k = 0; k < 384; ++k) acc = fmaf(gv[k], wr[k], acc);
  g1[g * 192 + j] = (acc > 0.f) ? acc : 0.01f * acc;
}

__global__ __launch_bounds__(256) void k_mlp2(const float* __restrict__ g1,
                                              const float* __restrict__ r2_w,
                                              const float* __restrict__ r2_b,
                                              float* __restrict__ out) {
  int idx = blockIdx.x * 256 + threadIdx.x;
  if (idx >= N_GRAPHSC * OUT_DIMC) return;
  int g = idx >> 4;
  int o = idx & 15;
  float acc = r2_b[o];
  const float* wr = r2_w + o * 192;
  const float* gr = g1 + g * 192;
  for (int k = 0; k < 192; ++k) acc = fmaf(gr[k], wr[k], acc);
  out[idx] = (acc > 0.f) ? acc : 0.01f * acc;
}

extern "C" void kernel_launch(void* const* d_in, const int* in_sizes, int n_in,
                              void* d_out, int out_size, void* d_ws, size_t ws_size,
                              hipStream_t stream) {
  const float* x      = (const float*)d_in[0];
  const int*   ei     = (const int*)d_in[1];
  const int*   batch  = (const int*)d_in[2];
  const float* emb_w  = (const float*)d_in[3];
  const float* emb_b  = (const float*)d_in[4];
  const float* W      = (const float*)d_in[5];
  const float* asym_b = (const float*)d_in[6];
  const float* lin_w  = (const float*)d_in[7];
  const float* r1_w   = (const float*)d_in[8];
  const float* r1_b   = (const float*)d_in[9];
  const float* r2_w   = (const float*)d_in[10];
  const float* r2_b   = (const float*)d_in[11];
  float* out = (float*)d_out;

  char* ws = (char*)d_ws;
  size_t off = 0;
  auto alloc = [&](size_t bytes) -> char* {
    char* p = ws + off;
    off += (bytes + 255) & ~(size_t)255;
    return p;
  };
  float* h      = (float*)alloc((size_t)N_NODESC * HIDC * 4);   // 51.2 MB
  float* agg    = (float*)alloc((size_t)N_NODESC * HIDC * 4);   // 51.2 MB
  float* MT     = (float*)alloc((size_t)2 * HIDC * HIDC * 4);   // 128 KB
  int* rowptr   = (int*)alloc((size_t)(N_NODESC + 1) * 4);
  int* cursor   = (int*)alloc((size_t)N_NODESC * 4);
  int* colidx   = (int*)alloc((size_t)N_EDGESC * 4);            // 6.4 MB
  float* part   = (float*)alloc((size_t)N_GRAPHSC * POOL_CHUNKS * 256 * 4);  // 1 MB
  float* pool   = (float*)alloc((size_t)N_GRAPHSC * 3 * HIDC * 4);
  float* g1buf  = (float*)alloc((size_t)N_GRAPHSC * 192 * 4);
  (void)ws_size; (void)in_sizes; (void)n_in; (void)out_size;

  const int* srcv = ei;
  const int* dstv = ei + N_EDGESC;

  hipMemsetAsync(cursor, 0, (size_t)N_NODESC * 4, stream);
  k_weights<<<(2 * HIDC * HIDC + 255) / 256, 256, 0, stream>>>(W, lin_w, MT);
  k_embed<<<(N_NODESC + 63) / 64, 256, 0, stream>>>(x, emb_w, emb_b, h);
  k_count<<<(N_EDGESC + 255) / 256, 256, 0, stream>>>(dstv, cursor);
  k_scan<<<1, 1024, 0, stream>>>(cursor, rowptr);
  k_fill<<<(N_EDGESC + 255) / 256, 256, 0, stream>>>(srcv, dstv, cursor, colidx);
  for (int it = 0; it < NUM_ITERSC; ++it) {
    k_gather<<<N_NODESC / 4, 256, 0, stream>>>(h, rowptr, colidx, agg);
    k_update<<<N_NODESC / 32, 256, 0, stream>>>(h, agg, MT, asym_b);
  }
  k_pool1<<<N_GRAPHSC * POOL_CHUNKS, 128, 0, stream>>>(h, batch, part);
  k_pool2<<<N_GRAPHSC, 128, 0, stream>>>(part, batch, pool);
  k_mlp1<<<N_GRAPHSC, 192, 0, stream>>>(pool, r1_w, r1_b, g1buf);
  k_mlp2<<<(N_GRAPHSC * OUT_DIMC + 255) / 256, 256, 0, stream>>>(g1buf, r2_w, r2_b, out);
}

// Round 3
// 1318.474 us; speedup vs baseline: 1.2639x; 1.1602x over previous
//
#include <hip/hip_runtime.h>
#include <hip/hip_bf16.h>
#include <math.h>

#define N_NODESC 100000
#define N_EDGESC 1600000
#define N_GRAPHSC 128
#define IN_DIMC 64
#define HIDC 128
#define OUT_DIMC 16
#define NUM_ITERSC 4
#define GAMMAC 0.1f
#define EPSC 0.1f
#define POOL_CHUNKS 8
#define SCAN_NB ((N_NODESC + 255) / 256)  // 391

// Build combined transposed weight MT[k][c], k in [0,256): k<128 -> aW[c][k] = W[c][k]-W[k][c]-gamma*I; k>=128 -> lin_w[c][k-128]
__global__ __launch_bounds__(256) void k_weights(const float* __restrict__ W,
                                                 const float* __restrict__ lin_w,
                                                 float* __restrict__ MT) {
  int idx = blockIdx.x * 256 + threadIdx.x;
  if (idx >= 2 * HIDC * HIDC) return;
  int k = idx >> 7;
  int c = idx & (HIDC - 1);
  float v;
  if (k < HIDC) {
    v = W[c * HIDC + k] - W[k * HIDC + c] - ((k == c) ? GAMMAC : 0.0f);
  } else {
    v = lin_w[c * HIDC + (k - HIDC)];
  }
  MT[idx] = v;
}

// h = x @ emb_w.T + emb_b   [N,64]@[64,128]
__global__ __launch_bounds__(256) void k_embed(const float* __restrict__ x,
                                               const float* __restrict__ emb_w,
                                               const float* __restrict__ emb_b,
                                               float* __restrict__ h) {
  __shared__ float wl[HIDC][IN_DIMC + 1];
  __shared__ float xl[8][IN_DIMC];
  int tid = threadIdx.x;
  for (int i = tid; i < HIDC * IN_DIMC; i += 256) {
    wl[i >> 6][i & 63] = emb_w[i];
  }
  int c = tid & (HIDC - 1);
  int half = tid >> 7;
  float bias = emb_b[c];
  int row0 = blockIdx.x * 64;
  __syncthreads();
  for (int rb = 0; rb < 64; rb += 8) {
    __syncthreads();
    for (int i = tid; i < 8 * IN_DIMC; i += 256) {
      int r = i >> 6;
      int gr = row0 + rb + r;
      xl[r][i & 63] = (gr < N_NODESC) ? x[(size_t)gr * IN_DIMC + (i & 63)] : 0.0f;
    }
    __syncthreads();
#pragma unroll
    for (int rr = 0; rr < 4; ++rr) {
      int r = half * 4 + rr;
      int gr = row0 + rb + r;
      if (gr < N_NODESC) {
        float acc = bias;
#pragma unroll
        for (int k = 0; k < IN_DIMC; ++k) acc = fmaf(xl[r][k], wl[c][k], acc);
        h[(size_t)gr * HIDC + c] = acc;
      }
    }
  }
}

__global__ __launch_bounds__(256) void k_count(const int* __restrict__ dst, int* __restrict__ cnt) {
  int e = blockIdx.x * 256 + threadIdx.x;
  if (e < N_EDGESC) atomicAdd(&cnt[dst[e]], 1);
}

// hierarchical scan, stage 1: per-block (256-elem) sums
__global__ __launch_bounds__(256) void k_scan1(const int* __restrict__ cnt, int* __restrict__ bsum) {
  __shared__ int red[256];
  int tid = threadIdx.x;
  int i = blockIdx.x * 256 + tid;
  red[tid] = (i < N_NODESC) ? cnt[i] : 0;
  __syncthreads();
#pragma unroll
  for (int off = 128; off > 0; off >>= 1) {
    if (tid < off) red[tid] += red[tid + off];
    __syncthreads();
  }
  if (tid == 0) bsum[blockIdx.x] = red[0];
}

// stage 2: exclusive scan of SCAN_NB block sums (single small block)
__global__ __launch_bounds__(512) void k_scan2(int* __restrict__ bsum, int* __restrict__ boff) {
  __shared__ int buf[512];
  int tid = threadIdx.x;
  int v = (tid < SCAN_NB) ? bsum[tid] : 0;
  buf[tid] = v;
  __syncthreads();
  for (int off = 1; off < 512; off <<= 1) {
    int t = (tid >= off) ? buf[tid - off] : 0;
    __syncthreads();
    buf[tid] += t;
    __syncthreads();
  }
  if (tid < SCAN_NB) boff[tid] = buf[tid] - v;  // exclusive
}

// stage 3: per-block exclusive scan + block offset -> rowptr, cursor
__global__ __launch_bounds__(256) void k_scan3(const int* __restrict__ cnt, const int* __restrict__ boff,
                                               int* __restrict__ rowptr, int* __restrict__ cursor) {
  __shared__ int buf[256];
  int tid = threadIdx.x;
  int i = blockIdx.x * 256 + tid;
  int v = (i < N_NODESC) ? cnt[i] : 0;
  buf[tid] = v;
  __syncthreads();
  for (int off = 1; off < 256; off <<= 1) {
    int t = (tid >= off) ? buf[tid - off] : 0;
    __syncthreads();
    buf[tid] += t;
    __syncthreads();
  }
  int excl = boff[blockIdx.x] + buf[tid] - v;
  if (i < N_NODESC) {
    rowptr[i] = excl;
    cursor[i] = excl;
    if (i == N_NODESC - 1) rowptr[N_NODESC] = excl + v;
  }
}

__global__ __launch_bounds__(256) void k_fill(const int* __restrict__ src, const int* __restrict__ dst,
                                              int* __restrict__ cursor, int* __restrict__ colidx) {
  int e = blockIdx.x * 256 + threadIdx.x;
  if (e < N_EDGESC) {
    int p = atomicAdd(&cursor[dst[e]], 1);
    colidx[p] = src[e];
  }
}

// agg[d] = sum over in-edges of h[src]; one wave per node, 2 cols per lane
__global__ __launch_bounds__(256) void k_gather(const float* __restrict__ h,
                                                const int* __restrict__ rowptr,
                                                const int* __restrict__ colidx,
                                                float* __restrict__ agg) {
  int node = blockIdx.x * 4 + (threadIdx.x >> 6);
  int lane = threadIdx.x & 63;
  if (node >= N_NODESC) return;
  int beg = rowptr[node];
  int end = rowptr[node + 1];
  float2 acc = make_float2(0.f, 0.f);
  int e = beg;
  for (; e + 2 <= end; e += 2) {
    int s0 = colidx[e], s1 = colidx[e + 1];
    float2 v0 = *(const float2*)(h + (size_t)s0 * HIDC + 2 * lane);
    float2 v1 = *(const float2*)(h + (size_t)s1 * HIDC + 2 * lane);
    acc.x += v0.x + v1.x;
    acc.y += v0.y + v1.y;
  }
  if (e < end) {
    int s0 = colidx[e];
    float2 v0 = *(const float2*)(h + (size_t)s0 * HIDC + 2 * lane);
    acc.x += v0.x;
    acc.y += v0.y;
  }
  *(float2*)(agg + (size_t)node * HIDC + 2 * lane) = acc;
}

// conv = [h|agg] @ MT (K=256), h += eps*tanh(conv + b). 32 rows/block, thread tile 4r x 4c.
__global__ __launch_bounds__(256) void k_update(float* __restrict__ h,
                                                const float* __restrict__ agg,
                                                const float* __restrict__ MT,
                                                const float* __restrict__ asym_b) {
  __shared__ __align__(16) float wl[64][HIDC + 4];  // [k][c] chunk, stride 132
  __shared__ __align__(16) float rl[32][64 + 4];    // [r][k] chunk, stride 68
  int tid = threadIdx.x;
  int tc = tid & 31;
  int tr = tid >> 5;
  int row0 = blockIdx.x * 32;
  float acc[4][4];
#pragma unroll
  for (int j = 0; j < 4; ++j) {
    acc[j][0] = acc[j][1] = acc[j][2] = acc[j][3] = 0.f;
  }
  for (int kc = 0; kc < 4; ++kc) {
    __syncthreads();
    for (int i = tid; i < 64 * HIDC; i += 256) {
      int k = i >> 7, c = i & (HIDC - 1);
      wl[k][c] = MT[(size_t)(kc * 64 + k) * HIDC + c];
    }
    const float* srcp = (kc < 2) ? h : agg;
    int coff = (kc & 1) * 64;
    for (int i = tid; i < 32 * 64; i += 256) {
      int r = i >> 6, kk = i & 63;
      rl[r][kk] = srcp[(size_t)(row0 + r) * HIDC + coff + kk];
    }
    __syncthreads();
#pragma unroll
    for (int k4 = 0; k4 < 64; k4 += 4) {
      float4 w0 = *(const float4*)&wl[k4 + 0][tc * 4];
      float4 w1 = *(const float4*)&wl[k4 + 1][tc * 4];
      float4 w2 = *(const float4*)&wl[k4 + 2][tc * 4];
      float4 w3 = *(const float4*)&wl[k4 + 3][tc * 4];
#pragma unroll
      for (int j = 0; j < 4; ++j) {
        float4 rv = *(const float4*)&rl[tr * 4 + j][k4];
        acc[j][0] = fmaf(rv.x, w0.x, fmaf(rv.y, w1.x, fmaf(rv.z, w2.x, fmaf(rv.w, w3.x, acc[j][0]))));
        acc[j][1] = fmaf(rv.x, w0.y, fmaf(rv.y, w1.y, fmaf(rv.z, w2.y, fmaf(rv.w, w3.y, acc[j][1]))));
        acc[j][2] = fmaf(rv.x, w0.z, fmaf(rv.y, w1.z, fmaf(rv.z, w2.z, fmaf(rv.w, w3.z, acc[j][2]))));
        acc[j][3] = fmaf(rv.x, w0.w, fmaf(rv.y, w1.w, fmaf(rv.z, w2.w, fmaf(rv.w, w3.w, acc[j][3]))));
      }
    }
  }
  float4 bias = *(const float4*)&asym_b[tc * 4];
#pragma unroll
  for (int j = 0; j < 4; ++j) {
    size_t r = (size_t)(row0 + tr * 4 + j);
    float4 hv = *(const float4*)&h[r * HIDC + tc * 4];
    float4 o;
    o.x = hv.x + EPSC * tanhf(acc[j][0] + bias.x);
    o.y = hv.y + EPSC * tanhf(acc[j][1] + bias.y);
    o.z = hv.z + EPSC * tanhf(acc[j][2] + bias.z);
    o.w = hv.w + EPSC * tanhf(acc[j][3] + bias.w);
    *(float4*)&h[r * HIDC + tc * 4] = o;
  }
}

__device__ __forceinline__ int lbound_batch(const int* __restrict__ a, int key) {
  int lo = 0, hi = N_NODESC;
  while (lo < hi) {
    int mid = (lo + hi) >> 1;
    if (a[mid] < key) lo = mid + 1;
    else hi = mid;
  }
  return lo;
}

// stage 1: partial [sum|max] per (graph, chunk); grid = G*POOL_CHUNKS blocks of 128
__global__ __launch_bounds__(128) void k_pool1(const float* __restrict__ h,
                                               const int* __restrict__ batch,
                                               float* __restrict__ part) {
  int g = blockIdx.x / POOL_CHUNKS;
  int j = blockIdx.x % POOL_CHUNKS;
  int c = threadIdx.x;
  int lo = lbound_batch(batch, g);
  int hi = lbound_batch(batch, g + 1);
  int n = hi - lo;
  int ch = (n + POOL_CHUNKS - 1) / POOL_CHUNKS;
  int b = lo + j * ch;
  int e = b + ch;
  if (e > hi) e = hi;
  float s = 0.f, m = -INFINITY;
  for (int i = b; i < e; ++i) {
    float v = h[(size_t)i * HIDC + c];
    s += v;
    m = fmaxf(m, v);
  }
  size_t o = ((size_t)g * POOL_CHUNKS + j) * 256;
  part[o + c] = s;
  part[o + 128 + c] = m;
}

// stage 2: combine chunks -> pool[g] = [add | max | mean]
__global__ __launch_bounds__(128) void k_pool2(const float* __restrict__ part,
                                               const int* __restrict__ batch,
                                               float* __restrict__ pool) {
  int g = blockIdx.x;
  int c = threadIdx.x;
  float s = 0.f, m = -INFINITY;
#pragma unroll
  for (int j = 0; j < POOL_CHUNKS; ++j) {
    size_t o = ((size_t)g * POOL_CHUNKS + j) * 256;
    s += part[o + c];
    m = fmaxf(m, part[o + 128 + c]);
  }
  int lo = lbound_batch(batch, g);
  int hi = lbound_batch(batch, g + 1);
  float cntf = (float)(hi - lo);
  pool[g * 384 + c] = s;
  pool[g * 384 + 128 + c] = m;
  pool[g * 384 + 256 + c] = s / fmaxf(cntf, 1.f);
}

__global__ __launch_bounds__(192) void k_mlp1(const float* __restrict__ pool,
                                              const float* __restrict__ r1_w,
                                              const float* __restrict__ r1_b,
                                              float* __restrict__ g1) {
  __shared__ float gv[384];
  int g = blockIdx.x;
  for (int i = threadIdx.x; i < 384; i += 192) gv[i] = pool[g * 384 + i];
  __syncthreads();
  int j = threadIdx.x;
  float acc = r1_b[j];
  const float* wr = r1_w + (size_t)j * 384;
#pragma unroll 4
  for (int k = 0; k < 384; ++k) acc = fmaf(gv[k], wr[k], acc);
  g1[g * 192 + j] = (acc > 0.f) ? acc : 0.01f * acc;
}

__global__ __launch_bounds__(256) void k_mlp2(const float* __restrict__ g1,
                                              const float* __restrict__ r2_w,
                                              const float* __restrict__ r2_b,
                                              float* __restrict__ out) {
  int idx = blockIdx.x * 256 + threadIdx.x;
  if (idx >= N_GRAPHSC * OUT_DIMC) return;
  int g = idx >> 4;
  int o = idx & 15;
  float acc = r2_b[o];
  const float* wr = r2_w + o * 192;
  const float* gr = g1 + g * 192;
  for (int k = 0; k < 192; ++k) acc = fmaf(gr[k], wr[k], acc);
  out[idx] = (acc > 0.f) ? acc : 0.01f * acc;
}

extern "C" void kernel_launch(void* const* d_in, const int* in_sizes, int n_in,
                              void* d_out, int out_size, void* d_ws, size_t ws_size,
                              hipStream_t stream) {
  const float* x      = (const float*)d_in[0];
  const int*   ei     = (const int*)d_in[1];
  const int*   batch  = (const int*)d_in[2];
  const float* emb_w  = (const float*)d_in[3];
  const float* emb_b  = (const float*)d_in[4];
  const float* W      = (const float*)d_in[5];
  const float* asym_b = (const float*)d_in[6];
  const float* lin_w  = (const float*)d_in[7];
  const float* r1_w   = (const float*)d_in[8];
  const float* r1_b   = (const float*)d_in[9];
  const float* r2_w   = (const float*)d_in[10];
  const float* r2_b   = (const float*)d_in[11];
  float* out = (float*)d_out;

  char* ws = (char*)d_ws;
  size_t off = 0;
  auto alloc = [&](size_t bytes) -> char* {
    char* p = ws + off;
    off += (bytes + 255) & ~(size_t)255;
    return p;
  };
  float* h      = (float*)alloc((size_t)N_NODESC * HIDC * 4);   // 51.2 MB
  float* agg    = (float*)alloc((size_t)N_NODESC * HIDC * 4);   // 51.2 MB
  float* MT     = (float*)alloc((size_t)2 * HIDC * HIDC * 4);   // 128 KB
  int* rowptr   = (int*)alloc((size_t)(N_NODESC + 1) * 4);
  int* cnt      = (int*)alloc((size_t)N_NODESC * 4);
  int* cursor   = (int*)alloc((size_t)N_NODESC * 4);
  int* bsum     = (int*)alloc((size_t)SCAN_NB * 4);
  int* boff     = (int*)alloc((size_t)SCAN_NB * 4);
  int* colidx   = (int*)alloc((size_t)N_EDGESC * 4);            // 6.4 MB
  float* part   = (float*)alloc((size_t)N_GRAPHSC * POOL_CHUNKS * 256 * 4);  // 1 MB
  float* pool   = (float*)alloc((size_t)N_GRAPHSC * 3 * HIDC * 4);
  float* g1buf  = (float*)alloc((size_t)N_GRAPHSC * 192 * 4);
  (void)ws_size; (void)in_sizes; (void)n_in; (void)out_size;

  const int* srcv = ei;
  const int* dstv = ei + N_EDGESC;

  hipMemsetAsync(cnt, 0, (size_t)N_NODESC * 4, stream);
  k_weights<<<(2 * HIDC * HIDC + 255) / 256, 256, 0, stream>>>(W, lin_w, MT);
  k_embed<<<(N_NODESC + 63) / 64, 256, 0, stream>>>(x, emb_w, emb_b, h);
  k_count<<<(N_EDGESC + 255) / 256, 256, 0, stream>>>(dstv, cnt);
  k_scan1<<<SCAN_NB, 256, 0, stream>>>(cnt, bsum);
  k_scan2<<<1, 512, 0, stream>>>(bsum, boff);
  k_scan3<<<SCAN_NB, 256, 0, stream>>>(cnt, boff, rowptr, cursor);
  k_fill<<<(N_EDGESC + 255) / 256, 256, 0, stream>>>(srcv, dstv, cursor, colidx);
  for (int it = 0; it < NUM_ITERSC; ++it) {
    k_gather<<<N_NODESC / 4, 256, 0, stream>>>(h, rowptr, colidx, agg);
    k_update<<<N_NODESC / 32, 256, 0, stream>>>(h, agg, MT, asym_b);
  }
  k_pool1<<<N_GRAPHSC * POOL_CHUNKS, 128, 0, stream>>>(h, batch, part);
  k_pool2<<<N_GRAPHSC, 128, 0, stream>>>(part, batch, pool);
  k_mlp1<<<N_GRAPHSC, 192, 0, stream>>>(pool, r1_w, r1_b, g1buf);
  k_mlp2<<<(N_GRAPHSC * OUT_DIMC + 255) / 256, 256, 0, stream>>>(g1buf, r2_w, r2_b, out);
}

// Round 4
// 922.517 us; speedup vs baseline: 1.8064x; 1.4292x over previous
//
#include <hip/hip_runtime.h>
#include <hip/hip_bf16.h>
#include <math.h>

#define N_NODESC 100000
#define N_EDGESC 1600000
#define N_GRAPHSC 128
#define IN_DIMC 64
#define HIDC 128
#define OUT_DIMC 16
#define NUM_ITERSC 4
#define GAMMAC 0.1f
#define EPSC 0.1f
#define POOL_CHUNKS 8
#define SCAN_NB ((N_NODESC + 255) / 256)  // 391
#define UPD_NB ((N_NODESC + 63) / 64)     // 1563

typedef __attribute__((ext_vector_type(8))) short bf16x8;
typedef __attribute__((ext_vector_type(4))) float f32x4;

__device__ __forceinline__ unsigned short f2bf(float f) {
  unsigned int u = __float_as_uint(f);
  unsigned int r = (u + 0x7fffu + ((u >> 16) & 1u)) >> 16;  // RNE
  return (unsigned short)r;
}
__device__ __forceinline__ float bflo(unsigned int u) { return __uint_as_float(u << 16); }
__device__ __forceinline__ float bfhi(unsigned int u) { return __uint_as_float(u & 0xffff0000u); }

// Pack combined weight directly into B-fragment order for mfma_f32_16x16x32_bf16.
// MTP[((ct*8+kc)*64+lane)*8+j] = M[k][c], k=kc*32+(lane>>4)*8+j, c=ct*16+(lane&15)
// where M[k][c] = (k<128) ? W[c][k]-W[k][c]-gamma*(k==c) : lin_w[c][k-128]
__global__ __launch_bounds__(256) void k_weights_pack(const float* __restrict__ W,
                                                      const float* __restrict__ lin_w,
                                                      unsigned short* __restrict__ MTP) {
  int idx = blockIdx.x * 256 + threadIdx.x;
  if (idx >= 32768) return;
  int j = idx & 7;
  int lane = (idx >> 3) & 63;
  int t = idx >> 9;  // ct*8+kc
  int kc = t & 7, ct = t >> 3;
  int k = kc * 32 + (lane >> 4) * 8 + j;
  int c = ct * 16 + (lane & 15);
  float v;
  if (k < HIDC) v = W[c * HIDC + k] - W[k * HIDC + c] - ((k == c) ? GAMMAC : 0.0f);
  else v = lin_w[c * HIDC + (k - HIDC)];
  MTP[idx] = f2bf(v);
}

// h = x @ emb_w.T + emb_b   [N,64]@[64,128]; writes fp32 h and bf16 shadow hb
__global__ __launch_bounds__(256) void k_embed(const float* __restrict__ x,
                                               const float* __restrict__ emb_w,
                                               const float* __restrict__ emb_b,
                                               float* __restrict__ h,
                                               unsigned short* __restrict__ hb) {
  __shared__ float wl[HIDC][IN_DIMC + 1];
  __shared__ float xl[8][IN_DIMC];
  int tid = threadIdx.x;
  for (int i = tid; i < HIDC * IN_DIMC; i += 256) {
    wl[i >> 6][i & 63] = emb_w[i];
  }
  int c = tid & (HIDC - 1);
  int half = tid >> 7;
  float bias = emb_b[c];
  int row0 = blockIdx.x * 64;
  __syncthreads();
  for (int rb = 0; rb < 64; rb += 8) {
    __syncthreads();
    for (int i = tid; i < 8 * IN_DIMC; i += 256) {
      int r = i >> 6;
      int gr = row0 + rb + r;
      xl[r][i & 63] = (gr < N_NODESC) ? x[(size_t)gr * IN_DIMC + (i & 63)] : 0.0f;
    }
    __syncthreads();
#pragma unroll
    for (int rr = 0; rr < 4; ++rr) {
      int r = half * 4 + rr;
      int gr = row0 + rb + r;
      if (gr < N_NODESC) {
        float acc = bias;
#pragma unroll
        for (int k = 0; k < IN_DIMC; ++k) acc = fmaf(xl[r][k], wl[c][k], acc);
        h[(size_t)gr * HIDC + c] = acc;
        hb[(size_t)gr * HIDC + c] = f2bf(acc);
      }
    }
  }
}

__global__ __launch_bounds__(256) void k_count(const int* __restrict__ dst, int* __restrict__ cnt) {
  int e = blockIdx.x * 256 + threadIdx.x;
  if (e < N_EDGESC) atomicAdd(&cnt[dst[e]], 1);
}

__global__ __launch_bounds__(256) void k_scan1(const int* __restrict__ cnt, int* __restrict__ bsum) {
  __shared__ int red[256];
  int tid = threadIdx.x;
  int i = blockIdx.x * 256 + tid;
  red[tid] = (i < N_NODESC) ? cnt[i] : 0;
  __syncthreads();
#pragma unroll
  for (int off = 128; off > 0; off >>= 1) {
    if (tid < off) red[tid] += red[tid + off];
    __syncthreads();
  }
  if (tid == 0) bsum[blockIdx.x] = red[0];
}

__global__ __launch_bounds__(512) void k_scan2(int* __restrict__ bsum, int* __restrict__ boff) {
  __shared__ int buf[512];
  int tid = threadIdx.x;
  int v = (tid < SCAN_NB) ? bsum[tid] : 0;
  buf[tid] = v;
  __syncthreads();
  for (int off = 1; off < 512; off <<= 1) {
    int t = (tid >= off) ? buf[tid - off] : 0;
    __syncthreads();
    buf[tid] += t;
    __syncthreads();
  }
  if (tid < SCAN_NB) boff[tid] = buf[tid] - v;
}

__global__ __launch_bounds__(256) void k_scan3(const int* __restrict__ cnt, const int* __restrict__ boff,
                                               int* __restrict__ rowptr, int* __restrict__ cursor) {
  __shared__ int buf[256];
  int tid = threadIdx.x;
  int i = blockIdx.x * 256 + tid;
  int v = (i < N_NODESC) ? cnt[i] : 0;
  buf[tid] = v;
  __syncthreads();
  for (int off = 1; off < 256; off <<= 1) {
    int t = (tid >= off) ? buf[tid - off] : 0;
    __syncthreads();
    buf[tid] += t;
    __syncthreads();
  }
  int excl = boff[blockIdx.x] + buf[tid] - v;
  if (i < N_NODESC) {
    rowptr[i] = excl;
    cursor[i] = excl;
    if (i == N_NODESC - 1) rowptr[N_NODESC] = excl + v;
  }
}

__global__ __launch_bounds__(256) void k_fill(const int* __restrict__ src, const int* __restrict__ dst,
                                              int* __restrict__ cursor, int* __restrict__ colidx) {
  int e = blockIdx.x * 256 + threadIdx.x;
  if (e < N_EDGESC) {
    int p = atomicAdd(&cursor[dst[e]], 1);
    colidx[p] = src[e];
  }
}

// agg over in-edges from bf16 shadow; one wave per node, 2 cols per lane (uint = 2 bf16)
__global__ __launch_bounds__(256) void k_gather_b(const unsigned int* __restrict__ hb32,
                                                  const int* __restrict__ rowptr,
                                                  const int* __restrict__ colidx,
                                                  unsigned int* __restrict__ aggb32) {
  int node = blockIdx.x * 4 + (threadIdx.x >> 6);
  int lane = threadIdx.x & 63;
  if (node >= N_NODESC) return;
  int beg = rowptr[node];
  int end = rowptr[node + 1];
  float ax = 0.f, ay = 0.f;
  int e = beg;
  for (; e + 2 <= end; e += 2) {
    int s0 = colidx[e], s1 = colidx[e + 1];
    unsigned int u0 = hb32[(size_t)s0 * 64 + lane];
    unsigned int u1 = hb32[(size_t)s1 * 64 + lane];
    ax += bflo(u0) + bflo(u1);
    ay += bfhi(u0) + bfhi(u1);
  }
  if (e < end) {
    unsigned int u0 = hb32[(size_t)colidx[e] * 64 + lane];
    ax += bflo(u0);
    ay += bfhi(u0);
  }
  aggb32[(size_t)node * 64 + lane] = (unsigned int)f2bf(ax) | ((unsigned int)f2bf(ay) << 16);
}

// conv = [hb|aggb] @ M^T via MFMA bf16 (K=256); h += eps*tanh(conv+b); refresh hb.
// 64 nodes/block, 4 waves: wave w -> rows w*16..w*16+15, all 8 col-tiles.
__global__ __launch_bounds__(256) void k_update_mfma(float* __restrict__ h,
                                                     unsigned short* __restrict__ hb,
                                                     const unsigned short* __restrict__ aggb,
                                                     const unsigned short* __restrict__ MTP,
                                                     const float* __restrict__ asym_b) {
  __shared__ __align__(16) unsigned char Als[64 * 512];  // 64 rows x 256 bf16 ([hb|aggb]), XOR-swizzled
  int tid = threadIdx.x;
  int r0 = blockIdx.x * 64;
  for (int i = tid; i < 2048; i += 256) {
    int row = i >> 5;
    int ck = i & 31;  // 16B chunk within 512B row
    int gr = r0 + row;
    uint4 v = make_uint4(0u, 0u, 0u, 0u);
    if (gr < N_NODESC) {
      if (ck < 16) v = ((const uint4*)(hb + (size_t)gr * HIDC))[ck];
      else v = ((const uint4*)(aggb + (size_t)gr * HIDC))[ck - 16];
    }
    *(uint4*)(Als + row * 512 + ((ck * 16) ^ ((row & 7) << 4))) = v;
  }
  __syncthreads();
  int lane = tid & 63, w = tid >> 6;
  int m = lane & 15, g = lane >> 4;
  int arow = w * 16 + m;
  bf16x8 a[8];
#pragma unroll
  for (int kc = 0; kc < 8; ++kc) {
    a[kc] = *(const bf16x8*)(Als + arow * 512 + ((kc * 64 + g * 16) ^ ((arow & 7) << 4)));
  }
  f32x4 acc[8];
#pragma unroll
  for (int ct = 0; ct < 8; ++ct) acc[ct] = (f32x4){0.f, 0.f, 0.f, 0.f};
#pragma unroll
  for (int ct = 0; ct < 8; ++ct) {
#pragma unroll
    for (int kc = 0; kc < 8; ++kc) {
      bf16x8 b = *(const bf16x8*)(MTP + ((size_t)((ct * 8 + kc) * 64 + lane)) * 8);
      acc[ct] = __builtin_amdgcn_mfma_f32_16x16x32_bf16(a[kc], b, acc[ct], 0, 0, 0);
    }
  }
  // C/D layout: col = lane&15, row = (lane>>4)*4 + j  [m89-verified]
#pragma unroll
  for (int ct = 0; ct < 8; ++ct) {
    int col = ct * 16 + m;
    float bias = asym_b[col];
#pragma unroll
    for (int j = 0; j < 4; ++j) {
      int grow = r0 + w * 16 + g * 4 + j;
      if (grow < N_NODESC) {
        size_t o = (size_t)grow * HIDC + col;
        float val = h[o] + EPSC * tanhf(acc[ct][j] + bias);
        h[o] = val;
        hb[o] = f2bf(val);
      }
    }
  }
}

__device__ __forceinline__ int lbound_batch(const int* __restrict__ a, int key) {
  int lo = 0, hi = N_NODESC;
  while (lo < hi) {
    int mid = (lo + hi) >> 1;
    if (a[mid] < key) lo = mid + 1;
    else hi = mid;
  }
  return lo;
}

__global__ __launch_bounds__(128) void k_pool1(const float* __restrict__ h,
                                               const int* __restrict__ batch,
                                               float* __restrict__ part) {
  int g = blockIdx.x / POOL_CHUNKS;
  int j = blockIdx.x % POOL_CHUNKS;
  int c = threadIdx.x;
  int lo = lbound_batch(batch, g);
  int hi = lbound_batch(batch, g + 1);
  int n = hi - lo;
  int ch = (n + POOL_CHUNKS - 1) / POOL_CHUNKS;
  int b = lo + j * ch;
  int e = b + ch;
  if (e > hi) e = hi;
  float s = 0.f, m = -INFINITY;
  for (int i = b; i < e; ++i) {
    float v = h[(size_t)i * HIDC + c];
    s += v;
    m = fmaxf(m, v);
  }
  size_t o = ((size_t)g * POOL_CHUNKS + j) * 256;
  part[o + c] = s;
  part[o + 128 + c] = m;
}

__global__ __launch_bounds__(128) void k_pool2(const float* __restrict__ part,
                                               const int* __restrict__ batch,
                                               float* __restrict__ pool) {
  int g = blockIdx.x;
  int c = threadIdx.x;
  float s = 0.f, m = -INFINITY;
#pragma unroll
  for (int j = 0; j < POOL_CHUNKS; ++j) {
    size_t o = ((size_t)g * POOL_CHUNKS + j) * 256;
    s += part[o + c];
    m = fmaxf(m, part[o + 128 + c]);
  }
  int lo = lbound_batch(batch, g);
  int hi = lbound_batch(batch, g + 1);
  float cntf = (float)(hi - lo);
  pool[g * 384 + c] = s;
  pool[g * 384 + 128 + c] = m;
  pool[g * 384 + 256 + c] = s / fmaxf(cntf, 1.f);
}

__global__ __launch_bounds__(192) void k_mlp1(const float* __restrict__ pool,
                                              const float* __restrict__ r1_w,
                                              const float* __restrict__ r1_b,
                                              float* __restrict__ g1) {
  __shared__ float gv[384];
  int g = blockIdx.x;
  for (int i = threadIdx.x; i < 384; i += 192) gv[i] = pool[g * 384 + i];
  __syncthreads();
  int j = threadIdx.x;
  float acc = r1_b[j];
  const float* wr = r1_w + (size_t)j * 384;
#pragma unroll 4
  for (int k = 0; k < 384; ++k) acc = fmaf(gv[k], wr[k], acc);
  g1[g * 192 + j] = (acc > 0.f) ? acc : 0.01f * acc;
}

__global__ __launch_bounds__(256) void k_mlp2(const float* __restrict__ g1,
                                              const float* __restrict__ r2_w,
                                              const float* __restrict__ r2_b,
                                              float* __restrict__ out) {
  int idx = blockIdx.x * 256 + threadIdx.x;
  if (idx >= N_GRAPHSC * OUT_DIMC) return;
  int g = idx >> 4;
  int o = idx & 15;
  float acc = r2_b[o];
  const float* wr = r2_w + o * 192;
  const float* gr = g1 + g * 192;
  for (int k = 0; k < 192; ++k) acc = fmaf(gr[k], wr[k], acc);
  out[idx] = (acc > 0.f) ? acc : 0.01f * acc;
}

extern "C" void kernel_launch(void* const* d_in, const int* in_sizes, int n_in,
                              void* d_out, int out_size, void* d_ws, size_t ws_size,
                              hipStream_t stream) {
  const float* x      = (const float*)d_in[0];
  const int*   ei     = (const int*)d_in[1];
  const int*   batch  = (const int*)d_in[2];
  const float* emb_w  = (const float*)d_in[3];
  const float* emb_b  = (const float*)d_in[4];
  const float* W      = (const float*)d_in[5];
  const float* asym_b = (const float*)d_in[6];
  const float* lin_w  = (const float*)d_in[7];
  const float* r1_w   = (const float*)d_in[8];
  const float* r1_b   = (const float*)d_in[9];
  const float* r2_w   = (const float*)d_in[10];
  const float* r2_b   = (const float*)d_in[11];
  float* out = (float*)d_out;

  char* ws = (char*)d_ws;
  size_t off = 0;
  auto alloc = [&](size_t bytes) -> char* {
    char* p = ws + off;
    off += (bytes + 255) & ~(size_t)255;
    return p;
  };
  float* h           = (float*)alloc((size_t)N_NODESC * HIDC * 4);           // 51.2 MB
  unsigned short* hb = (unsigned short*)alloc((size_t)N_NODESC * HIDC * 2);  // 25.6 MB
  unsigned short* ab = (unsigned short*)alloc((size_t)N_NODESC * HIDC * 2);  // 25.6 MB
  unsigned short* MTP = (unsigned short*)alloc((size_t)32768 * 2);           // 64 KB
  int* rowptr   = (int*)alloc((size_t)(N_NODESC + 1) * 4);
  int* cnt      = (int*)alloc((size_t)N_NODESC * 4);
  int* cursor   = (int*)alloc((size_t)N_NODESC * 4);
  int* bsum     = (int*)alloc((size_t)SCAN_NB * 4);
  int* boff     = (int*)alloc((size_t)SCAN_NB * 4);
  int* colidx   = (int*)alloc((size_t)N_EDGESC * 4);            // 6.4 MB
  float* part   = (float*)alloc((size_t)N_GRAPHSC * POOL_CHUNKS * 256 * 4);  // 1 MB
  float* pool   = (float*)alloc((size_t)N_GRAPHSC * 3 * HIDC * 4);
  float* g1buf  = (float*)alloc((size_t)N_GRAPHSC * 192 * 4);
  (void)ws_size; (void)in_sizes; (void)n_in; (void)out_size;

  const int* srcv = ei;
  const int* dstv = ei + N_EDGESC;

  hipMemsetAsync(cnt, 0, (size_t)N_NODESC * 4, stream);
  k_weights_pack<<<128, 256, 0, stream>>>(W, lin_w, MTP);
  k_embed<<<(N_NODESC + 63) / 64, 256, 0, stream>>>(x, emb_w, emb_b, h, hb);
  k_count<<<(N_EDGESC + 255) / 256, 256, 0, stream>>>(dstv, cnt);
  k_scan1<<<SCAN_NB, 256, 0, stream>>>(cnt, bsum);
  k_scan2<<<1, 512, 0, stream>>>(bsum, boff);
  k_scan3<<<SCAN_NB, 256, 0, stream>>>(cnt, boff, rowptr, cursor);
  k_fill<<<(N_EDGESC + 255) / 256, 256, 0, stream>>>(srcv, dstv, cursor, colidx);
  for (int it = 0; it < NUM_ITERSC; ++it) {
    k_gather_b<<<N_NODESC / 4, 256, 0, stream>>>((const unsigned int*)hb, rowptr, colidx,
                                                 (unsigned int*)ab);
    k_update_mfma<<<UPD_NB, 256, 0, stream>>>(h, hb, ab, MTP, asym_b);
  }
  k_pool1<<<N_GRAPHSC * POOL_CHUNKS, 128, 0, stream>>>(h, batch, part);
  k_pool2<<<N_GRAPHSC, 128, 0, stream>>>(part, batch, pool);
  k_mlp1<<<N_GRAPHSC, 192, 0, stream>>>(pool, r1_w, r1_b, g1buf);
  k_mlp2<<<(N_GRAPHSC * OUT_DIMC + 255) / 256, 256, 0, stream>>>(g1buf, r2_w, r2_b, out);
}

// Round 5
// 794.791 us; speedup vs baseline: 2.0966x; 1.1607x over previous
//
#include <hip/hip_runtime.h>
#include <hip/hip_bf16.h>
#include <math.h>

#define N_NODESC 100000
#define N_EDGESC 1600000
#define N_GRAPHSC 128
#define IN_DIMC 64
#define HIDC 128
#define OUT_DIMC 16
#define NUM_ITERSC 4
#define GAMMAC 0.1f
#define EPSC 0.1f
#define POOL_CHUNKS 8
#define UPD_NB ((N_NODESC + 63) / 64)

// bucketed CSR build
#define NBUK 98                         // ceil(100000/1024), bucket = dst>>10
#define EPB 4096                        // edges per hist/scatter block
#define NBLK ((N_EDGESC + EPB - 1) / EPB)   // 391
#define NHIST (NBUK * NBLK)             // 38318
#define S1NB ((NHIST + 255) / 256)      // 150

typedef __attribute__((ext_vector_type(8))) short bf16x8;
typedef __attribute__((ext_vector_type(4))) float f32x4;

__device__ __forceinline__ unsigned short f2bf(float f) {
  unsigned int u = __float_as_uint(f);
  unsigned int r = (u + 0x7fffu + ((u >> 16) & 1u)) >> 16;  // RNE
  return (unsigned short)r;
}
__device__ __forceinline__ float bflo(unsigned int u) { return __uint_as_float(u << 16); }
__device__ __forceinline__ float bfhi(unsigned int u) { return __uint_as_float(u & 0xffff0000u); }

// Pack combined weight directly into B-fragment order for mfma_f32_16x16x32_bf16.
__global__ __launch_bounds__(256) void k_weights_pack(const float* __restrict__ W,
                                                      const float* __restrict__ lin_w,
                                                      unsigned short* __restrict__ MTP) {
  int idx = blockIdx.x * 256 + threadIdx.x;
  if (idx >= 32768) return;
  int j = idx & 7;
  int lane = (idx >> 3) & 63;
  int t = idx >> 9;  // ct*8+kc
  int kc = t & 7, ct = t >> 3;
  int k = kc * 32 + (lane >> 4) * 8 + j;
  int c = ct * 16 + (lane & 15);
  float v;
  if (k < HIDC) v = W[c * HIDC + k] - W[k * HIDC + c] - ((k == c) ? GAMMAC : 0.0f);
  else v = lin_w[c * HIDC + (k - HIDC)];
  MTP[idx] = f2bf(v);
}

// h = x @ emb_w.T + emb_b; writes fp32 h and bf16 shadow hb
__global__ __launch_bounds__(256) void k_embed(const float* __restrict__ x,
                                               const float* __restrict__ emb_w,
                                               const float* __restrict__ emb_b,
                                               float* __restrict__ h,
                                               unsigned short* __restrict__ hb) {
  __shared__ float wl[HIDC][IN_DIMC + 1];
  __shared__ float xl[8][IN_DIMC];
  int tid = threadIdx.x;
  for (int i = tid; i < HIDC * IN_DIMC; i += 256) {
    wl[i >> 6][i & 63] = emb_w[i];
  }
  int c = tid & (HIDC - 1);
  int half = tid >> 7;
  float bias = emb_b[c];
  int row0 = blockIdx.x * 64;
  __syncthreads();
  for (int rb = 0; rb < 64; rb += 8) {
    __syncthreads();
    for (int i = tid; i < 8 * IN_DIMC; i += 256) {
      int r = i >> 6;
      int gr = row0 + rb + r;
      xl[r][i & 63] = (gr < N_NODESC) ? x[(size_t)gr * IN_DIMC + (i & 63)] : 0.0f;
    }
    __syncthreads();
#pragma unroll
    for (int rr = 0; rr < 4; ++rr) {
      int r = half * 4 + rr;
      int gr = row0 + rb + r;
      if (gr < N_NODESC) {
        float acc = bias;
#pragma unroll
        for (int k = 0; k < IN_DIMC; ++k) acc = fmaf(xl[r][k], wl[c][k], acc);
        h[(size_t)gr * HIDC + c] = acc;
        hb[(size_t)gr * HIDC + c] = f2bf(acc);
      }
    }
  }
}

// ---- bucketed CSR build ----
// pass 1: per-(block,bucket) histogram; histg[bu*NBLK + blk]
__global__ __launch_bounds__(256) void k_hist(const int* __restrict__ dst, int* __restrict__ histg) {
  __shared__ int hl[NBUK];
  int tid = threadIdx.x;
  for (int i = tid; i < NBUK; i += 256) hl[i] = 0;
  __syncthreads();
  int base = blockIdx.x * EPB;
  int end = base + EPB;
  if (end > N_EDGESC) end = N_EDGESC;
  for (int e = base + tid; e < end; e += 256) atomicAdd(&hl[dst[e] >> 10], 1);
  __syncthreads();
  for (int i = tid; i < NBUK; i += 256) histg[i * NBLK + blockIdx.x] = hl[i];
}

// generic hierarchical exclusive scan over NHIST ints
__global__ __launch_bounds__(256) void k_s1(const int* __restrict__ in, int* __restrict__ bsum) {
  __shared__ int red[256];
  int tid = threadIdx.x;
  int i = blockIdx.x * 256 + tid;
  red[tid] = (i < NHIST) ? in[i] : 0;
  __syncthreads();
#pragma unroll
  for (int off = 128; off > 0; off >>= 1) {
    if (tid < off) red[tid] += red[tid + off];
    __syncthreads();
  }
  if (tid == 0) bsum[blockIdx.x] = red[0];
}

__global__ __launch_bounds__(256) void k_s2(int* __restrict__ bsum, int* __restrict__ boff) {
  __shared__ int buf[256];
  int tid = threadIdx.x;
  int v = (tid < S1NB) ? bsum[tid] : 0;
  buf[tid] = v;
  __syncthreads();
  for (int off = 1; off < 256; off <<= 1) {
    int t = (tid >= off) ? buf[tid - off] : 0;
    __syncthreads();
    buf[tid] += t;
    __syncthreads();
  }
  if (tid < S1NB) boff[tid] = buf[tid] - v;
}

__global__ __launch_bounds__(256) void k_s3(const int* __restrict__ in, const int* __restrict__ boff,
                                            int* __restrict__ out) {
  __shared__ int buf[256];
  int tid = threadIdx.x;
  int i = blockIdx.x * 256 + tid;
  int v = (i < NHIST) ? in[i] : 0;
  buf[tid] = v;
  __syncthreads();
  for (int off = 1; off < 256; off <<= 1) {
    int t = (tid >= off) ? buf[tid - off] : 0;
    __syncthreads();
    buf[tid] += t;
    __syncthreads();
  }
  if (i < NHIST) out[i] = boff[blockIdx.x] + buf[tid] - v;
}

// pass 2: scatter edges into bucket-contiguous ebuf, packed (dstloc<<17 | src)
__global__ __launch_bounds__(256) void k_scatter(const int* __restrict__ src, const int* __restrict__ dst,
                                                 const int* __restrict__ hoff, unsigned int* __restrict__ ebuf) {
  __shared__ int cur[NBUK];
  int tid = threadIdx.x;
  for (int i = tid; i < NBUK; i += 256) cur[i] = hoff[i * NBLK + blockIdx.x];
  __syncthreads();
  int base = blockIdx.x * EPB;
  int end = base + EPB;
  if (end > N_EDGESC) end = N_EDGESC;
  for (int e = base + tid; e < end; e += 256) {
    int d = dst[e];
    int bu = d >> 10;
    int pos = atomicAdd(&cur[bu], 1);
    ebuf[pos] = ((unsigned int)(d & 1023) << 17) | (unsigned int)src[e];
  }
}

// pass 3: per-bucket local CSR: rowptr + colidx (writes confined to bucket window)
__global__ __launch_bounds__(256) void k_csr(const unsigned int* __restrict__ ebuf,
                                             const int* __restrict__ hoff,
                                             int* __restrict__ rowptr, int* __restrict__ colidx) {
  __shared__ int lcnt[1024];
  __shared__ int lcur[1024];
  __shared__ int ssum[256];
  int b = blockIdx.x, tid = threadIdx.x;
  int ebeg = hoff[b * NBLK];
  int eend = (b + 1 < NBUK) ? hoff[(b + 1) * NBLK] : N_EDGESC;
  for (int i = tid; i < 1024; i += 256) lcnt[i] = 0;
  __syncthreads();
  for (int e = ebeg + tid; e < eend; e += 256) atomicAdd(&lcnt[ebuf[e] >> 17], 1);
  __syncthreads();
  int c0 = lcnt[tid * 4 + 0], c1 = lcnt[tid * 4 + 1], c2 = lcnt[tid * 4 + 2], c3 = lcnt[tid * 4 + 3];
  int s = c0 + c1 + c2 + c3;
  ssum[tid] = s;
  __syncthreads();
  for (int off = 1; off < 256; off <<= 1) {
    int t = (tid >= off) ? ssum[tid - off] : 0;
    __syncthreads();
    ssum[tid] += t;
    __syncthreads();
  }
  int excl = ssum[tid] - s;
  int node0 = (b << 10) + tid * 4;
  int ex = excl;
  lcur[tid * 4 + 0] = ex; if (node0 + 0 < N_NODESC) rowptr[node0 + 0] = ebeg + ex; ex += c0;
  lcur[tid * 4 + 1] = ex; if (node0 + 1 < N_NODESC) rowptr[node0 + 1] = ebeg + ex; ex += c1;
  lcur[tid * 4 + 2] = ex; if (node0 + 2 < N_NODESC) rowptr[node0 + 2] = ebeg + ex; ex += c2;
  lcur[tid * 4 + 3] = ex; if (node0 + 3 < N_NODESC) rowptr[node0 + 3] = ebeg + ex;
  __syncthreads();
  for (int e = ebeg + tid; e < eend; e += 256) {
    unsigned int u = ebuf[e];
    int pos = atomicAdd(&lcur[u >> 17], 1);
    colidx[ebeg + pos] = (int)(u & 0x1FFFFu);
  }
  if (b == 0 && tid == 0) rowptr[N_NODESC] = N_EDGESC;
}

// agg over in-edges from bf16 shadow; one wave per node, 2 cols per lane (uint = 2 bf16)
__global__ __launch_bounds__(256) void k_gather_b(const unsigned int* __restrict__ hb32,
                                                  const int* __restrict__ rowptr,
                                                  const int* __restrict__ colidx,
                                                  unsigned int* __restrict__ aggb32) {
  int node = blockIdx.x * 4 + (threadIdx.x >> 6);
  int lane = threadIdx.x & 63;
  if (node >= N_NODESC) return;
  int beg = rowptr[node];
  int end = rowptr[node + 1];
  float ax = 0.f, ay = 0.f;
  int e = beg;
  for (; e + 2 <= end; e += 2) {
    int s0 = colidx[e], s1 = colidx[e + 1];
    unsigned int u0 = hb32[(size_t)s0 * 64 + lane];
    unsigned int u1 = hb32[(size_t)s1 * 64 + lane];
    ax += bflo(u0) + bflo(u1);
    ay += bfhi(u0) + bfhi(u1);
  }
  if (e < end) {
    unsigned int u0 = hb32[(size_t)colidx[e] * 64 + lane];
    ax += bflo(u0);
    ay += bfhi(u0);
  }
  aggb32[(size_t)node * 64 + lane] = (unsigned int)f2bf(ax) | ((unsigned int)f2bf(ay) << 16);
}

// conv = [hb|aggb] @ M^T via MFMA bf16 (K=256); h += eps*tanh(conv+b); refresh hb.
__global__ __launch_bounds__(256) void k_update_mfma(float* __restrict__ h,
                                                     unsigned short* __restrict__ hb,
                                                     const unsigned short* __restrict__ aggb,
                                                     const unsigned short* __restrict__ MTP,
                                                     const float* __restrict__ asym_b) {
  __shared__ __align__(16) unsigned char Als[64 * 512];
  int tid = threadIdx.x;
  int r0 = blockIdx.x * 64;
  for (int i = tid; i < 2048; i += 256) {
    int row = i >> 5;
    int ck = i & 31;
    int gr = r0 + row;
    uint4 v = make_uint4(0u, 0u, 0u, 0u);
    if (gr < N_NODESC) {
      if (ck < 16) v = ((const uint4*)(hb + (size_t)gr * HIDC))[ck];
      else v = ((const uint4*)(aggb + (size_t)gr * HIDC))[ck - 16];
    }
    *(uint4*)(Als + row * 512 + ((ck * 16) ^ ((row & 7) << 4))) = v;
  }
  __syncthreads();
  int lane = tid & 63, w = tid >> 6;
  int m = lane & 15, g = lane >> 4;
  int arow = w * 16 + m;
  bf16x8 a[8];
#pragma unroll
  for (int kc = 0; kc < 8; ++kc) {
    a[kc] = *(const bf16x8*)(Als + arow * 512 + ((kc * 64 + g * 16) ^ ((arow & 7) << 4)));
  }
  f32x4 acc[8];
#pragma unroll
  for (int ct = 0; ct < 8; ++ct) acc[ct] = (f32x4){0.f, 0.f, 0.f, 0.f};
#pragma unroll
  for (int ct = 0; ct < 8; ++ct) {
#pragma unroll
    for (int kc = 0; kc < 8; ++kc) {
      bf16x8 b = *(const bf16x8*)(MTP + ((size_t)((ct * 8 + kc) * 64 + lane)) * 8);
      acc[ct] = __builtin_amdgcn_mfma_f32_16x16x32_bf16(a[kc], b, acc[ct], 0, 0, 0);
    }
  }
#pragma unroll
  for (int ct = 0; ct < 8; ++ct) {
    int col = ct * 16 + m;
    float bias = asym_b[col];
#pragma unroll
    for (int j = 0; j < 4; ++j) {
      int grow = r0 + w * 16 + g * 4 + j;
      if (grow < N_NODESC) {
        size_t o = (size_t)grow * HIDC + col;
        float val = h[o] + EPSC * tanhf(acc[ct][j] + bias);
        h[o] = val;
        hb[o] = f2bf(val);
      }
    }
  }
}

__device__ __forceinline__ int lbound_batch(const int* __restrict__ a, int key) {
  int lo = 0, hi = N_NODESC;
  while (lo < hi) {
    int mid = (lo + hi) >> 1;
    if (a[mid] < key) lo = mid + 1;
    else hi = mid;
  }
  return lo;
}

__global__ __launch_bounds__(128) void k_pool1(const float* __restrict__ h,
                                               const int* __restrict__ batch,
                                               float* __restrict__ part) {
  int g = blockIdx.x / POOL_CHUNKS;
  int j = blockIdx.x % POOL_CHUNKS;
  int c = threadIdx.x;
  int lo = lbound_batch(batch, g);
  int hi = lbound_batch(batch, g + 1);
  int n = hi - lo;
  int ch = (n + POOL_CHUNKS - 1) / POOL_CHUNKS;
  int b = lo + j * ch;
  int e = b + ch;
  if (e > hi) e = hi;
  float s = 0.f, m = -INFINITY;
  for (int i = b; i < e; ++i) {
    float v = h[(size_t)i * HIDC + c];
    s += v;
    m = fmaxf(m, v);
  }
  size_t o = ((size_t)g * POOL_CHUNKS + j) * 256;
  part[o + c] = s;
  part[o + 128 + c] = m;
}

__global__ __launch_bounds__(128) void k_pool2(const float* __restrict__ part,
                                               const int* __restrict__ batch,
                                               float* __restrict__ pool) {
  int g = blockIdx.x;
  int c = threadIdx.x;
  float s = 0.f, m = -INFINITY;
#pragma unroll
  for (int j = 0; j < POOL_CHUNKS; ++j) {
    size_t o = ((size_t)g * POOL_CHUNKS + j) * 256;
    s += part[o + c];
    m = fmaxf(m, part[o + 128 + c]);
  }
  int lo = lbound_batch(batch, g);
  int hi = lbound_batch(batch, g + 1);
  float cntf = (float)(hi - lo);
  pool[g * 384 + c] = s;
  pool[g * 384 + 128 + c] = m;
  pool[g * 384 + 256 + c] = s / fmaxf(cntf, 1.f);
}

__global__ __launch_bounds__(192) void k_mlp1(const float* __restrict__ pool,
                                              const float* __restrict__ r1_w,
                                              const float* __restrict__ r1_b,
                                              float* __restrict__ g1) {
  __shared__ float gv[384];
  int g = blockIdx.x;
  for (int i = threadIdx.x; i < 384; i += 192) gv[i] = pool[g * 384 + i];
  __syncthreads();
  int j = threadIdx.x;
  float acc = r1_b[j];
  const float* wr = r1_w + (size_t)j * 384;
#pragma unroll 4
  for (int k = 0; k < 384; ++k) acc = fmaf(gv[k], wr[k], acc);
  g1[g * 192 + j] = (acc > 0.f) ? acc : 0.01f * acc;
}

__global__ __launch_bounds__(256) void k_mlp2(const float* __restrict__ g1,
                                              const float* __restrict__ r2_w,
                                              const float* __restrict__ r2_b,
                                              float* __restrict__ out) {
  int idx = blockIdx.x * 256 + threadIdx.x;
  if (idx >= N_GRAPHSC * OUT_DIMC) return;
  int g = idx >> 4;
  int o = idx & 15;
  float acc = r2_b[o];
  const float* wr = r2_w + o * 192;
  const float* gr = g1 + g * 192;
  for (int k = 0; k < 192; ++k) acc = fmaf(gr[k], wr[k], acc);
  out[idx] = (acc > 0.f) ? acc : 0.01f * acc;
}

extern "C" void kernel_launch(void* const* d_in, const int* in_sizes, int n_in,
                              void* d_out, int out_size, void* d_ws, size_t ws_size,
                              hipStream_t stream) {
  const float* x      = (const float*)d_in[0];
  const int*   ei     = (const int*)d_in[1];
  const int*   batch  = (const int*)d_in[2];
  const float* emb_w  = (const float*)d_in[3];
  const float* emb_b  = (const float*)d_in[4];
  const float* W      = (const float*)d_in[5];
  const float* asym_b = (const float*)d_in[6];
  const float* lin_w  = (const float*)d_in[7];
  const float* r1_w   = (const float*)d_in[8];
  const float* r1_b   = (const float*)d_in[9];
  const float* r2_w   = (const float*)d_in[10];
  const float* r2_b   = (const float*)d_in[11];
  float* out = (float*)d_out;

  char* ws = (char*)d_ws;
  size_t off = 0;
  auto alloc = [&](size_t bytes) -> char* {
    char* p = ws + off;
    off += (bytes + 255) & ~(size_t)255;
    return p;
  };
  float* h           = (float*)alloc((size_t)N_NODESC * HIDC * 4);           // 51.2 MB
  unsigned short* hb = (unsigned short*)alloc((size_t)N_NODESC * HIDC * 2);  // 25.6 MB
  unsigned short* ab = (unsigned short*)alloc((size_t)N_NODESC * HIDC * 2);  // 25.6 MB
  unsigned short* MTP = (unsigned short*)alloc((size_t)32768 * 2);           // 64 KB
  int* rowptr   = (int*)alloc((size_t)(N_NODESC + 1) * 4);
  int* colidx   = (int*)alloc((size_t)N_EDGESC * 4);            // 6.4 MB
  unsigned int* ebuf = (unsigned int*)alloc((size_t)N_EDGESC * 4);  // 6.4 MB
  int* histg    = (int*)alloc((size_t)NHIST * 4);               // 150 KB
  int* hoff     = (int*)alloc((size_t)NHIST * 4);               // 150 KB
  int* bsum     = (int*)alloc((size_t)S1NB * 4);
  int* boff     = (int*)alloc((size_t)S1NB * 4);
  float* part   = (float*)alloc((size_t)N_GRAPHSC * POOL_CHUNKS * 256 * 4);  // 1 MB
  float* pool   = (float*)alloc((size_t)N_GRAPHSC * 3 * HIDC * 4);
  float* g1buf  = (float*)alloc((size_t)N_GRAPHSC * 192 * 4);
  (void)ws_size; (void)in_sizes; (void)n_in; (void)out_size;

  const int* srcv = ei;
  const int* dstv = ei + N_EDGESC;

  k_weights_pack<<<128, 256, 0, stream>>>(W, lin_w, MTP);
  k_embed<<<(N_NODESC + 63) / 64, 256, 0, stream>>>(x, emb_w, emb_b, h, hb);
  k_hist<<<NBLK, 256, 0, stream>>>(dstv, histg);
  k_s1<<<S1NB, 256, 0, stream>>>(histg, bsum);
  k_s2<<<1, 256, 0, stream>>>(bsum, boff);
  k_s3<<<S1NB, 256, 0, stream>>>(histg, boff, hoff);
  k_scatter<<<NBLK, 256, 0, stream>>>(srcv, dstv, hoff, ebuf);
  k_csr<<<NBUK, 256, 0, stream>>>(ebuf, hoff, rowptr, colidx);
  for (int it = 0; it < NUM_ITERSC; ++it) {
    k_gather_b<<<N_NODESC / 4, 256, 0, stream>>>((const unsigned int*)hb, rowptr, colidx,
                                                 (unsigned int*)ab);
    k_update_mfma<<<UPD_NB, 256, 0, stream>>>(h, hb, ab, MTP, asym_b);
  }
  k_pool1<<<N_GRAPHSC * POOL_CHUNKS, 128, 0, stream>>>(h, batch, part);
  k_pool2<<<N_GRAPHSC, 128, 0, stream>>>(part, batch, pool);
  k_mlp1<<<N_GRAPHSC, 192, 0, stream>>>(pool, r1_w, r1_b, g1buf);
  k_mlp2<<<(N_GRAPHSC * OUT_DIMC + 255) / 256, 256, 0, stream>>>(g1buf, r2_w, r2_b, out);
}